// Round 1
// baseline (731.090 us; speedup 1.0000x reference)
//
#include <hip/hip_runtime.h>

#define N_NODES 100000
#define N_EDGES 3200000
#define N_PAIRS 1000000
#define SCAN_BLK 256
#define NBLK ((N_NODES + SCAN_BLK - 1) / SCAN_BLK)   // 391

// ---------------- CSR build ----------------

__global__ void k_zero(int* __restrict__ p, int n) {
  int i = blockIdx.x * blockDim.x + threadIdx.x;
  if (i < n) p[i] = 0;
}

__global__ void k_hist(const int* __restrict__ dst, int* __restrict__ cnt) {
  int e = blockIdx.x * blockDim.x + threadIdx.x;
  if (e < N_EDGES) atomicAdd(&cnt[dst[e]], 1);
}

__global__ void k_scan_block(const int* __restrict__ cnt, int* __restrict__ tmp_scan,
                             int* __restrict__ blk_sums) {
  __shared__ int sh[SCAN_BLK];
  int tid = threadIdx.x;
  int i = blockIdx.x * SCAN_BLK + tid;
  int v = (i < N_NODES) ? cnt[i] : 0;
  sh[tid] = v;
  __syncthreads();
  for (int off = 1; off < SCAN_BLK; off <<= 1) {
    int t = (tid >= off) ? sh[tid - off] : 0;
    __syncthreads();
    sh[tid] += t;
    __syncthreads();
  }
  if (i < N_NODES) tmp_scan[i] = sh[tid];
  if (tid == SCAN_BLK - 1) blk_sums[blockIdx.x] = sh[tid];
}

__global__ void k_scan_top(const int* __restrict__ blk_sums, int* __restrict__ blk_off) {
  __shared__ int sh[512];
  int tid = threadIdx.x;
  int v = (tid < NBLK) ? blk_sums[tid] : 0;
  sh[tid] = v;
  __syncthreads();
  for (int off = 1; off < 512; off <<= 1) {
    int t = (tid >= off) ? sh[tid - off] : 0;
    __syncthreads();
    sh[tid] += t;
    __syncthreads();
  }
  if (tid < NBLK) blk_off[tid] = sh[tid] - v;   // exclusive
}

__global__ void k_finalize(const int* __restrict__ cnt, const int* __restrict__ tmp_scan,
                           const int* __restrict__ blk_off,
                           int* __restrict__ row_ptr, int* __restrict__ write_off) {
  int i = blockIdx.x * blockDim.x + threadIdx.x;
  if (i < N_NODES) {
    int incl = tmp_scan[i] + blk_off[i >> 8];   // 256 = 1<<8
    row_ptr[i + 1] = incl;
    write_off[i] = incl - cnt[i];               // exclusive = row start
    if (i == 0) row_ptr[0] = 0;
  }
}

__global__ void k_scatter(const int* __restrict__ src, const int* __restrict__ dst,
                          int* __restrict__ write_off, int* __restrict__ csr) {
  int e = blockIdx.x * blockDim.x + threadIdx.x;
  if (e < N_EDGES) {
    int pos = atomicAdd(&write_off[dst[e]], 1);
    csr[pos] = src[e];
  }
}

// ---------------- Fused SAGE layers (1 wave per node) ----------------

// layer 1: F_in=32, F_out=64. Lanes: f = lane&31, half = lane>>5 processes
// every other neighbor; halves combined with shfl_xor(32).
__global__ void __launch_bounds__(256) k_layer1(
    const float* __restrict__ x, const int* __restrict__ row_ptr,
    const int* __restrict__ csr, const float* __restrict__ Wl,
    const float* __restrict__ bl, const float* __restrict__ Wr,
    float* __restrict__ out)
{
  int gid = blockIdx.x * blockDim.x + threadIdx.x;
  int n = gid >> 6;
  int lane = threadIdx.x & 63;
  if (n >= N_NODES) return;
  int f = lane & 31;
  int half = lane >> 5;
  int beg = row_ptr[n], end = row_ptr[n + 1];
  int deg = end - beg;
  float s = 0.f;
  int i = beg + half;
  for (; i + 6 < end; i += 8) {                 // 4 neighbors per half per iter (ILP)
    int i0 = csr[i], i1 = csr[i + 2], i2 = csr[i + 4], i3 = csr[i + 6];
    s += x[i0 * 32 + f];
    s += x[i1 * 32 + f];
    s += x[i2 * 32 + f];
    s += x[i3 * 32 + f];
  }
  for (; i < end; i += 2) s += x[csr[i] * 32 + f];
  s += __shfl_xor(s, 32);                       // combine the two halves
  float mean = (deg > 0) ? s / (float)deg : 0.f;
  float self = x[n * 32 + f];
  float acc = bl[lane];
#pragma unroll
  for (int f2 = 0; f2 < 32; ++f2) {
    float mf = __shfl(mean, f2);
    float sf = __shfl(self, f2);
    acc = fmaf(mf, Wl[f2 * 64 + lane], acc);
    acc = fmaf(sf, Wr[f2 * 64 + lane], acc);
  }
  out[n * 64 + lane] = fmaxf(acc, 0.f);
}

// layer 2: F_in=64, F_out=64. lane = feature.
__global__ void __launch_bounds__(256) k_layer2(
    const float* __restrict__ hin, const int* __restrict__ row_ptr,
    const int* __restrict__ csr, const float* __restrict__ Wl,
    const float* __restrict__ bl, const float* __restrict__ Wr,
    float* __restrict__ out)
{
  int gid = blockIdx.x * blockDim.x + threadIdx.x;
  int n = gid >> 6;
  int lane = threadIdx.x & 63;
  if (n >= N_NODES) return;
  int beg = row_ptr[n], end = row_ptr[n + 1];
  int deg = end - beg;
  float s = 0.f;
  int i = beg;
  for (; i + 3 < end; i += 4) {                 // 4-deep ILP on the gather chain
    int i0 = csr[i], i1 = csr[i + 1], i2 = csr[i + 2], i3 = csr[i + 3];
    s += hin[i0 * 64 + lane];
    s += hin[i1 * 64 + lane];
    s += hin[i2 * 64 + lane];
    s += hin[i3 * 64 + lane];
  }
  for (; i < end; ++i) s += hin[csr[i] * 64 + lane];
  float mean = (deg > 0) ? s / (float)deg : 0.f;
  float self = hin[n * 64 + lane];
  float acc = bl[lane];
#pragma unroll
  for (int ff = 0; ff < 64; ++ff) {
    acc = fmaf(__shfl(mean, ff), Wl[ff * 64 + lane], acc);
    acc = fmaf(__shfl(self, ff), Wr[ff * 64 + lane], acc);
  }
  out[n * 64 + lane] = fmaxf(acc, 0.f);
}

// ---------------- Edge scorer: wave = 8 edges, 8 lanes/edge ----------------

__global__ void __launch_bounds__(256) k_edge(
    const float* __restrict__ h, const int* __restrict__ pairs,
    const float* __restrict__ Wh, const float* __restrict__ bh,
    float* __restrict__ out)
{
  int gid = blockIdx.x * blockDim.x + threadIdx.x;
  int wave = gid >> 6;
  int lane = threadIdx.x & 63;
  int j = lane >> 3, c = lane & 7;
  int e = wave * 8 + j;
  if (e >= N_PAIRS) return;
  int sN = pairs[2 * e];
  int dN = pairs[2 * e + 1];
  const float4* hs = (const float4*)(h + sN * 64 + c * 8);
  const float4* hd = (const float4*)(h + dN * 64 + c * 8);
  float4 a0 = hs[0], a1 = hs[1];
  float4 b0 = hd[0], b1 = hd[1];
  const float4* wsp = (const float4*)(Wh + c * 8);
  float4 w0 = wsp[0], w1 = wsp[1];
  const float4* wdp = (const float4*)(Wh + 64 + c * 8);
  float4 w2 = wdp[0], w3 = wdp[1];
  float acc = a0.x * w0.x + a0.y * w0.y + a0.z * w0.z + a0.w * w0.w
            + a1.x * w1.x + a1.y * w1.y + a1.z * w1.z + a1.w * w1.w
            + b0.x * w2.x + b0.y * w2.y + b0.z * w2.z + b0.w * w2.w
            + b1.x * w3.x + b1.y * w3.y + b1.z * w3.z + b1.w * w3.w;
  acc += __shfl_xor(acc, 1);
  acc += __shfl_xor(acc, 2);
  acc += __shfl_xor(acc, 4);
  if (c == 0) out[e] = acc + bh[0];
}

// ---------------- launch ----------------

extern "C" void kernel_launch(void* const* d_in, const int* in_sizes, int n_in,
                              void* d_out, int out_size, void* d_ws, size_t ws_size,
                              hipStream_t stream)
{
  const float* x   = (const float*)d_in[0];
  const int*   ei  = (const int*)d_in[1];
  const int* pairs = (const int*)d_in[2];
  const float* Wl1 = (const float*)d_in[3];
  const float* bl1 = (const float*)d_in[4];
  const float* Wr1 = (const float*)d_in[5];
  const float* Wl2 = (const float*)d_in[6];
  const float* bl2 = (const float*)d_in[7];
  const float* Wr2 = (const float*)d_in[8];
  const float* Wh  = (const float*)d_in[9];
  const float* bh  = (const float*)d_in[10];
  float* out = (float*)d_out;

  const int* src = ei;             // edge_index[0]
  const int* dst = ei + N_EDGES;   // edge_index[1]

  char* p = (char*)d_ws;
  auto alloc = [&](size_t bytes) {
    char* r = p;
    p += (bytes + 255) & ~(size_t)255;
    return r;
  };
  int*   cnt      = (int*)alloc((size_t)N_NODES * 4);
  int*   tmp_scan = (int*)alloc((size_t)N_NODES * 4);
  int*   blk_sums = (int*)alloc(512 * 4);
  int*   blk_off  = (int*)alloc(512 * 4);
  int*   row_ptr  = (int*)alloc((size_t)(N_NODES + 1) * 4);
  int*   woff     = (int*)alloc((size_t)N_NODES * 4);
  int*   csr      = (int*)alloc((size_t)N_EDGES * 4);
  float* h1       = (float*)alloc((size_t)N_NODES * 64 * 4);
  float* h2       = (float*)alloc((size_t)N_NODES * 64 * 4);

  k_zero<<<(N_NODES + 255) / 256, 256, 0, stream>>>(cnt, N_NODES);
  k_hist<<<(N_EDGES + 255) / 256, 256, 0, stream>>>(dst, cnt);
  k_scan_block<<<NBLK, SCAN_BLK, 0, stream>>>(cnt, tmp_scan, blk_sums);
  k_scan_top<<<1, 512, 0, stream>>>(blk_sums, blk_off);
  k_finalize<<<(N_NODES + 255) / 256, 256, 0, stream>>>(cnt, tmp_scan, blk_off, row_ptr, woff);
  k_scatter<<<(N_EDGES + 255) / 256, 256, 0, stream>>>(src, dst, woff, csr);

  k_layer1<<<(N_NODES * 64) / 256, 256, 0, stream>>>(x,  row_ptr, csr, Wl1, bl1, Wr1, h1);
  k_layer2<<<(N_NODES * 64) / 256, 256, 0, stream>>>(h1, row_ptr, csr, Wl2, bl2, Wr2, h2);
  k_edge<<<(N_PAIRS * 8) / 256, 256, 0, stream>>>(h2, pairs, Wh, bh, out);
}